// Round 9
// baseline (558.903 us; speedup 1.0000x reference)
//
#include <hip/hip_runtime.h>
#include <math.h>

#define N_NODES  50000
#define N_HEDGES 50000
#define NNZ_     800000
#define IN_CH    512
#define HID_CH   256
#define OUT_CH   64
#define M_PAD    50048   // 391*128 rows of staging slack for global_load_lds
#define NBK      391     // buckets of 128 ids: ceil(50000/128)
#define BPC      12500   // gather256c blocks per chunk (4 rows/block * 12500 = 50000)

// prep kernel grid partition (256-thread blocks)
#define CVT_BLK  25000   // 50000*512/4 float4 / 256
#define BH_BLK   98
#define PK1_BLK  512     // 512*256/256
#define PK2_BLK  64      // 256*64/256

typedef __attribute__((ext_vector_type(8))) short bf16x8;
typedef __attribute__((ext_vector_type(4))) float f32x4;

__device__ __forceinline__ unsigned short f2bf(float f) {
    union { float f; unsigned u; } v; v.f = f;
    unsigned r = v.u + 0x7FFFu + ((v.u >> 16) & 1u);   // round-to-nearest-even
    return (unsigned short)(r >> 16);
}
__device__ __forceinline__ float bf2f(unsigned short u) {
    union { unsigned u; float f; } v; v.u = (unsigned)u << 16; return v.f;
}

#define GLL16(g, l)                                                            \
    __builtin_amdgcn_global_load_lds(                                          \
        (const __attribute__((address_space(1))) void*)(g),                    \
        (__attribute__((address_space(3))) void*)(l), 16, 0, 0)

// ---- prep: fused  x->bf16 convert | bucket histogram | W1 pack | W2 pack ----
__global__ void prep_kernel(const float* __restrict__ x, unsigned short* __restrict__ x_bf,
                            const float* __restrict__ W1, unsigned short* __restrict__ Wp1,
                            const float* __restrict__ W2, unsigned short* __restrict__ Wp2,
                            const int* __restrict__ ni, const int* __restrict__ hi,
                            int* __restrict__ bcntN, int* __restrict__ bcntH) {
    const int blk = blockIdx.x;
    const int t = threadIdx.x;
    if (blk < CVT_BLK) {
        const long i = (long)blk * 256 + t;
        const float4 v = *(const float4*)(x + i * 4);
        ushort4 o;
        o.x = f2bf(v.x); o.y = f2bf(v.y); o.z = f2bf(v.z); o.w = f2bf(v.w);
        *(ushort4*)(x_bf + i * 4) = o;
    } else if (blk < CVT_BLK + BH_BLK) {
        __shared__ int lh[NBK], ln[NBK];
        for (int k = t; k < NBK; k += 256) { lh[k] = 0; ln[k] = 0; }
        __syncthreads();
        const int bb = blk - CVT_BLK;
        for (int i4 = bb * 256 + t; i4 < NNZ_ / 4; i4 += BH_BLK * 256) {
            const int4 nv = *(const int4*)(ni + i4 * 4);
            const int4 hv = *(const int4*)(hi + i4 * 4);
            atomicAdd(&ln[nv.x >> 7], 1); atomicAdd(&ln[nv.y >> 7], 1);
            atomicAdd(&ln[nv.z >> 7], 1); atomicAdd(&ln[nv.w >> 7], 1);
            atomicAdd(&lh[hv.x >> 7], 1); atomicAdd(&lh[hv.y >> 7], 1);
            atomicAdd(&lh[hv.z >> 7], 1); atomicAdd(&lh[hv.w >> 7], 1);
        }
        __syncthreads();
        for (int k = t; k < NBK; k += 256) {
            if (ln[k]) atomicAdd(&bcntN[k], ln[k]);
            if (lh[k]) atomicAdd(&bcntH[k], lh[k]);
        }
    } else if (blk < CVT_BLK + BH_BLK + PK1_BLK) {
        const int i = (blk - (CVT_BLK + BH_BLK)) * 256 + t;
        const int kt = i / (HID_CH * 32);
        const int r  = i % (HID_CH * 32);
        const int n  = r >> 5, kk = r & 31;
        Wp1[i] = f2bf(W1[(size_t)(kt * 32 + kk) * HID_CH + n]);
    } else {
        const int i = (blk - (CVT_BLK + BH_BLK + PK1_BLK)) * 256 + t;
        const int kt = i / (OUT_CH * 32);
        const int r  = i % (OUT_CH * 32);
        const int n  = r >> 5, kk = r & 31;
        Wp2[i] = f2bf(W2[(size_t)(kt * 32 + kk) * OUT_CH + n]);
    }
}

// ---- 391-entry exclusive scan; writes bucket starts + a mutable cursor copy ----
__global__ void scan391_kernel(const int* __restrict__ cA, int* __restrict__ offA,
                               int* __restrict__ curA,
                               const int* __restrict__ cB, int* __restrict__ offB,
                               int* __restrict__ curB) {
    const int* cnt = blockIdx.x ? cB : cA;
    int* off = blockIdx.x ? offB : offA;
    int* cur = blockIdx.x ? curB : curA;
    __shared__ int sbuf[512];
    const int t = threadIdx.x;      // 512 threads
    const int v = (t < NBK) ? cnt[t] : 0;
    sbuf[t] = v;
    __syncthreads();
    #pragma unroll
    for (int d = 1; d < 512; d <<= 1) {
        int u = (t >= d) ? sbuf[t - d] : 0;
        __syncthreads();
        sbuf[t] += u;
        __syncthreads();
    }
    if (t < NBK) { off[t] = sbuf[t] - v; cur[t] = sbuf[t] - v; }
    if (t == NBK - 1) off[NBK] = sbuf[t];
}

// ---- bin: scatter packed records into bucket slices (mutates bcur cursors) ----
__global__ void bin_kernel(const int* __restrict__ ni, const int* __restrict__ hi,
                           int* __restrict__ bcurN, int* __restrict__ bcurH,
                           unsigned* __restrict__ recN, unsigned* __restrict__ recH) {
    __shared__ int cH[NBK], cN[NBK], bH[NBK], bN[NBK];
    for (int t = threadIdx.x; t < NBK; t += blockDim.x) { cH[t] = 0; cN[t] = 0; }
    __syncthreads();
    const int gid = blockIdx.x * blockDim.x + threadIdx.x;
    const int i0 = gid * 4;
    int4 nv, hv;
    const bool act = (i0 < NNZ_);
    if (act) {
        nv = *(const int4*)(ni + i0);
        hv = *(const int4*)(hi + i0);
        atomicAdd(&cN[nv.x >> 7], 1); atomicAdd(&cN[nv.y >> 7], 1);
        atomicAdd(&cN[nv.z >> 7], 1); atomicAdd(&cN[nv.w >> 7], 1);
        atomicAdd(&cH[hv.x >> 7], 1); atomicAdd(&cH[hv.y >> 7], 1);
        atomicAdd(&cH[hv.z >> 7], 1); atomicAdd(&cH[hv.w >> 7], 1);
    }
    __syncthreads();
    for (int t = threadIdx.x; t < NBK; t += blockDim.x) {
        bH[t] = cH[t] ? atomicAdd(&bcurH[t], cH[t]) : 0;
        bN[t] = cN[t] ? atomicAdd(&bcurN[t], cN[t]) : 0;
    }
    __syncthreads();
    for (int t = threadIdx.x; t < NBK; t += blockDim.x) { cH[t] = bH[t]; cN[t] = bN[t]; }
    __syncthreads();
    if (act) {
        int nn[4] = {nv.x, nv.y, nv.z, nv.w};
        int hh[4] = {hv.x, hv.y, hv.z, hv.w};
        #pragma unroll
        for (int k = 0; k < 4; ++k) {
            int p = atomicAdd(&cH[hh[k] >> 7], 1);
            recH[p] = ((unsigned)(hh[k] & 127) << 16) | (unsigned)nn[k];
            p = atomicAdd(&cN[nn[k] >> 7], 1);
            recN[p] = ((unsigned)(nn[k] & 127) << 16) | (unsigned)hh[k];
        }
    }
}

// ---- buildcsr: per bucket — count, 128-prefix-scan, off+inv write, col fill ----
__global__ void buildcsr_kernel(const int* __restrict__ bstartH, const unsigned* __restrict__ recH,
                                int* __restrict__ offH, int* __restrict__ colH,
                                float* __restrict__ Binv,
                                const int* __restrict__ bstartN, const unsigned* __restrict__ recN,
                                int* __restrict__ offN, int* __restrict__ colN,
                                float* __restrict__ Dinv) {
    int b = blockIdx.x;
    const int* bstart; const unsigned* rec; int* off; int* col; float* inv;
    if (b < NBK) { bstart = bstartH; rec = recH; off = offH; col = colH; inv = Binv; }
    else { b -= NBK; bstart = bstartN; rec = recN; off = offN; col = colN; inv = Dinv; }
    const int s = bstart[b], e = bstart[b + 1];
    const int t = threadIdx.x;
    __shared__ int lc[128], ps[128], cur[128];
    if (t < 128) lc[t] = 0;
    __syncthreads();
    for (int i = s + t; i < e; i += 256) atomicAdd(&lc[rec[i] >> 16], 1);
    __syncthreads();
    if (t < 128) ps[t] = lc[t];
    __syncthreads();
    #pragma unroll
    for (int d = 1; d < 128; d <<= 1) {
        int v = (t >= d && t < 128) ? ps[t - d] : 0;
        __syncthreads();
        if (t < 128) ps[t] += v;
        __syncthreads();
    }
    if (t < 128) {
        const int excl = s + ps[t] - lc[t];
        cur[t] = excl;
        const int id = b * 128 + t;
        if (id < N_NODES) {
            off[id] = excl;
            inv[id] = lc[t] > 0 ? 1.f / (float)lc[t] : 0.f;
        }
    }
    if (b == NBK - 1 && t == 255) off[N_NODES] = bstart[NBK];
    __syncthreads();
    for (int i = s + t; i < e; i += 256) {
        const unsigned r = rec[i];
        const int p = atomicAdd(&cur[r >> 16], 1);
        col[p] = (int)(r & 0xFFFFu);
    }
}

// ---------------- MFMA bf16 GEMM: C[M,N] = A[M,K] @ W[K,N], bf16 output -----------
// CHUNK: write C in [chunk64][M_PAD][64] layout (for chunked gathers).
template <int BN, bool CHUNK>
__global__ void mfma_gemm_kernel(const unsigned short* __restrict__ A,
                                 const unsigned short* __restrict__ Wp,
                                 unsigned short* __restrict__ C, int M, int N, int K) {
    constexpr int NT = BN / 32;
    __shared__ unsigned short As[128 * 32];
    __shared__ unsigned short Bs[BN * 32];

    const int tid  = threadIdx.x;
    const int wave = tid >> 6;
    const int lane = tid & 63;
    const int wr = wave >> 1;
    const int wc = wave & 1;
    const int quad = lane >> 4;
    const int l15  = lane & 15;
    const int row0 = blockIdx.y * 128;
    const int col0 = blockIdx.x * BN;

    const size_t a_g0   = (size_t)(row0 + wave * 16 + (lane >> 2)) * K + (lane & 3) * 8;
    const int    a_l0   = (wave * 16 + (lane >> 2)) * 32 + (lane & 3) * 8;
    const size_t b_gbase = ((size_t)col0 + wave * 16 + (lane >> 2)) * 32 + (lane & 3) * 8;
    const int    b_l0   = (wave * 16 + (lane >> 2)) * 32 + (lane & 3) * 8;

    f32x4 acc[4][NT];
    #pragma unroll
    for (int mt = 0; mt < 4; ++mt)
        #pragma unroll
        for (int nt = 0; nt < NT; ++nt)
            acc[mt][nt] = (f32x4)0.f;

    const int KT = K / 32;
    for (int kt = 0; kt < KT; ++kt) {
        __syncthreads();
        GLL16(A + a_g0 + (size_t)kt * 32, As + a_l0);
        GLL16(A + a_g0 + (size_t)(kt * 32) + (size_t)64 * K, As + a_l0 + 64 * 32);
        const size_t bk = (size_t)kt * N * 32;
        GLL16(Wp + bk + b_gbase, Bs + b_l0);
        if (BN == 128)
            GLL16(Wp + bk + b_gbase + 64 * 32, Bs + b_l0 + 64 * 32);
        __syncthreads();

        bf16x8 af[4], bf[NT];
        #pragma unroll
        for (int mt = 0; mt < 4; ++mt)
            af[mt] = *(const bf16x8*)(As + (wr * 64 + mt * 16 + l15) * 32 + quad * 8);
        #pragma unroll
        for (int nt = 0; nt < NT; ++nt)
            bf[nt] = *(const bf16x8*)(Bs + (wc * (BN / 2) + nt * 16 + l15) * 32 + quad * 8);
        #pragma unroll
        for (int mt = 0; mt < 4; ++mt)
            #pragma unroll
            for (int nt = 0; nt < NT; ++nt)
                acc[mt][nt] = __builtin_amdgcn_mfma_f32_16x16x32_bf16(
                    af[mt], bf[nt], acc[mt][nt], 0, 0, 0);
    }

    // epilogue: C layout col=lane&15, row=quad*4+reg
    #pragma unroll
    for (int mt = 0; mt < 4; ++mt) {
        const int gr0 = row0 + wr * 64 + mt * 16 + quad * 4;
        #pragma unroll
        for (int nt = 0; nt < NT; ++nt) {
            #pragma unroll
            for (int r = 0; r < 4; ++r) {
                int gr = gr0 + r;
                if (CHUNK) {
                    // chunk is wave-constant: (col0 + wc*64) / 64
                    const size_t base = (size_t)(col0 / 64 + wc) * ((size_t)M_PAD * 64);
                    C[base + (size_t)gr * 64 + nt * 16 + l15] = f2bf(acc[mt][nt][r]);
                } else {
                    const int gc = col0 + wc * (BN / 2) + nt * 16 + l15;
                    if (gr < M) C[(size_t)gr * N + gc] = f2bf(acc[mt][nt][r]);
                }
            }
        }
    }
}

// ------- chunked gather segment-sum, 256 ch as 4x64-ch passes, 8-deep unrolled -----
// src: [chunk][M_PAD][64].  EPI=false: dst [chunk][M_PAD][64].
// EPI=true: bias+relu, dst row-major [row][256].
template <bool EPI>
__global__ void gather256c_kernel(const unsigned short* __restrict__ src,
                                  unsigned short* __restrict__ dst,
                                  const int* __restrict__ off, const int* __restrict__ col,
                                  const float* __restrict__ scale,
                                  const float* __restrict__ bias, int nrows) {
    const int chunk = blockIdx.x / BPC;
    const int row = (blockIdx.x % BPC) * 4 + (threadIdx.x >> 6);
    const int lane = threadIdx.x & 63;
    const unsigned short* sb = src + (size_t)chunk * ((size_t)M_PAD * 64) + lane;
    int s = off[row], e = off[row + 1];
    float acc = 0.f;
    int j = s;
    for (; j + 7 < e; j += 8) {
        const float v0 = bf2f(sb[col[j]     << 6]);
        const float v1 = bf2f(sb[col[j + 1] << 6]);
        const float v2 = bf2f(sb[col[j + 2] << 6]);
        const float v3 = bf2f(sb[col[j + 3] << 6]);
        const float v4 = bf2f(sb[col[j + 4] << 6]);
        const float v5 = bf2f(sb[col[j + 5] << 6]);
        const float v6 = bf2f(sb[col[j + 6] << 6]);
        const float v7 = bf2f(sb[col[j + 7] << 6]);
        acc += ((v0 + v1) + (v2 + v3)) + ((v4 + v5) + (v6 + v7));
    }
    for (; j < e; ++j) acc += bf2f(sb[col[j] << 6]);
    float r = acc * scale[row];
    if (EPI) {
        r = fmaxf(r + bias[chunk * 64 + lane], 0.f);
        dst[(size_t)row * HID_CH + chunk * 64 + lane] = f2bf(r);
    } else {
        dst[(size_t)chunk * ((size_t)M_PAD * 64) + (size_t)row * 64 + lane] = f2bf(r);
    }
}

// ---------------- gather segment-sum, 64 channels, bf16, 8-deep unrolled -----------
template <bool LSM>
__global__ void gather64_kernel(const unsigned short* __restrict__ src, void* __restrict__ dstv,
                                const int* __restrict__ off, const int* __restrict__ col,
                                const float* __restrict__ scale,
                                const float* __restrict__ bias, int nrows) {
    int row = blockIdx.x * (blockDim.x >> 6) + (threadIdx.x >> 6);
    if (row >= nrows) return;
    int lane = threadIdx.x & 63;
    int s = off[row], e = off[row + 1];
    float acc = 0.f;
    int j = s;
    for (; j + 7 < e; j += 8) {
        const float v0 = bf2f(src[((size_t)col[j]     << 6) + lane]);
        const float v1 = bf2f(src[((size_t)col[j + 1] << 6) + lane]);
        const float v2 = bf2f(src[((size_t)col[j + 2] << 6) + lane]);
        const float v3 = bf2f(src[((size_t)col[j + 3] << 6) + lane]);
        const float v4 = bf2f(src[((size_t)col[j + 4] << 6) + lane]);
        const float v5 = bf2f(src[((size_t)col[j + 5] << 6) + lane]);
        const float v6 = bf2f(src[((size_t)col[j + 6] << 6) + lane]);
        const float v7 = bf2f(src[((size_t)col[j + 7] << 6) + lane]);
        acc += ((v0 + v1) + (v2 + v3)) + ((v4 + v5) + (v6 + v7));
    }
    for (; j < e; ++j) acc += bf2f(src[((size_t)col[j] << 6) + lane]);
    float v = acc * scale[row];
    if (LSM) {
        v += bias[lane];
        float m = v;
        #pragma unroll
        for (int o = 32; o >= 1; o >>= 1) m = fmaxf(m, __shfl_xor(m, o));
        float ex = expf(v - m);
        float su = ex;
        #pragma unroll
        for (int o = 32; o >= 1; o >>= 1) su += __shfl_xor(su, o);
        ((float*)dstv)[(size_t)row * OUT_CH + lane] = v - m - logf(su);
    } else {
        ((unsigned short*)dstv)[(size_t)row * OUT_CH + lane] = f2bf(v);
    }
}

extern "C" void kernel_launch(void* const* d_in, const int* in_sizes, int n_in,
                              void* d_out, int out_size, void* d_ws, size_t ws_size,
                              hipStream_t stream) {
    const float* x  = (const float*)d_in[0];
    const int*   ei = (const int*)d_in[1];
    const float* W1 = (const float*)d_in[2];
    const float* b1 = (const float*)d_in[3];
    const float* W2 = (const float*)d_in[4];
    const float* b2 = (const float*)d_in[5];
    float* out = (float*)d_out;

    const int* node_idx  = ei;
    const int* hedge_idx = ei + NNZ_;

    const size_t RCAP = (size_t)M_PAD * IN_CH / 2;   // floats; 51.25 MB per region
    float* regionA = (float*)d_ws;
    float* regionB = regionA + RCAP;
    float* Dinv = regionB + RCAP;
    float* Binv = Dinv + N_NODES;
    int* offN = (int*)(Binv + N_HEDGES);             // N_NODES+1
    int* offH = offN + N_NODES + 1;                  // N_HEDGES+1
    int* colN = offH + N_HEDGES + 1;                 // NNZ
    int* colH = colN + NNZ_;                         // NNZ
    unsigned short* Wp1 = (unsigned short*)(colH + NNZ_);
    unsigned short* Wp2 = Wp1 + IN_CH * HID_CH;
    int* bcntH   = (int*)(Wp2 + HID_CH * OUT_CH);    // 400
    int* bcntN   = bcntH + 400;                      // 400
    int* bstartH = bcntN + 400;                      // 392 used
    int* bstartN = bstartH + 400;
    int* bcurH   = bstartN + 400;
    int* bcurN   = bcurH + 400;

    // transient CSR-build records alias regionA (dead until GEMM1 writes h1)
    unsigned* recH = (unsigned*)regionA;             // NNZ
    unsigned* recN = recH + NNZ_;                    // NNZ

    unsigned short* x_bf  = (unsigned short*)regionB;            // M_PAD x 512
    unsigned short* h1c   = (unsigned short*)regionA;            // [4][M_PAD][64] chunked
    unsigned short* m1c   = (unsigned short*)regionB;            // [4][M_PAD][64] (x dead)
    unsigned short* h2_bf = (unsigned short*)regionA;            // M_PAD x 256 (h1 dead)
    unsigned short* g_bf  = (unsigned short*)regionB;            // 50000 x 64 (m1 dead)
    unsigned short* m2_bf = (unsigned short*)regionB + (size_t)M_PAD * OUT_CH; // 50000 x 64

    // ---- fused prep + CSR build ----
    hipMemsetAsync(bcntH, 0, 800 * sizeof(int), stream);
    prep_kernel<<<CVT_BLK + BH_BLK + PK1_BLK + PK2_BLK, 256, 0, stream>>>(
        x, x_bf, W1, Wp1, W2, Wp2, node_idx, hedge_idx, bcntN, bcntH);
    scan391_kernel<<<2, 512, 0, stream>>>(bcntH, bstartH, bcurH, bcntN, bstartN, bcurN);
    bin_kernel<<<200, 1024, 0, stream>>>(node_idx, hedge_idx, bcurN, bcurH, recN, recH);
    buildcsr_kernel<<<2 * NBK, 256, 0, stream>>>(bstartH, recH, offH, colH, Binv,
                                                 bstartN, recN, offN, colN, Dinv);

    // ---- layer 1: h1 = x @ W1 (MFMA bf16, chunked C) ----
    mfma_gemm_kernel<128, true><<<dim3(HID_CH / 128, (N_NODES + 127) / 128), 256, 0, stream>>>(
        x_bf, Wp1, h1c, N_NODES, HID_CH, IN_CH);
    gather256c_kernel<false><<<4 * BPC, 256, 0, stream>>>(
        h1c, m1c, offH, colH, Binv, nullptr, N_HEDGES);
    gather256c_kernel<true><<<4 * BPC, 256, 0, stream>>>(
        m1c, h2_bf, offN, colN, Dinv, b1, N_NODES);

    // ---- layer 2: g = h2 @ W2 (MFMA bf16, row-major C) ----
    mfma_gemm_kernel<64, false><<<dim3(OUT_CH / 64, (N_NODES + 127) / 128), 256, 0, stream>>>(
        h2_bf, Wp2, g_bf, N_NODES, OUT_CH, HID_CH);
    gather64_kernel<false><<<(N_HEDGES + 3) / 4, 256, 0, stream>>>(
        g_bf, m2_bf, offH, colH, Binv, nullptr, N_HEDGES);
    gather64_kernel<true><<<(N_NODES + 3) / 4, 256, 0, stream>>>(
        m2_bf, out, offN, colN, Dinv, b2, N_NODES);
}

// Round 10
// 418.770 us; speedup vs baseline: 1.3346x; 1.3346x over previous
//
#include <hip/hip_runtime.h>
#include <math.h>

#define N_NODES  50000
#define N_HEDGES 50000
#define NNZ_     800000
#define IN_CH    512
#define HID_CH   256
#define OUT_CH   64
#define M_PAD    50048   // 391*128 rows of staging slack for global_load_lds
#define NBK      391     // buckets of 128 ids: ceil(50000/128)

// prep kernel grid partition (256-thread blocks)
#define CVT_BLK  25000   // 50000*512/4 float4 / 256
#define BH_BLK   98
#define PK1_BLK  512     // 512*256/256
#define PK2_BLK  64      // 256*64/256

typedef __attribute__((ext_vector_type(8))) short bf16x8;
typedef __attribute__((ext_vector_type(4))) float f32x4;

__device__ __forceinline__ unsigned short f2bf(float f) {
    union { float f; unsigned u; } v; v.f = f;
    unsigned r = v.u + 0x7FFFu + ((v.u >> 16) & 1u);   // round-to-nearest-even
    return (unsigned short)(r >> 16);
}
__device__ __forceinline__ float bf2f(unsigned short u) {
    union { unsigned u; float f; } v; v.u = (unsigned)u << 16; return v.f;
}

#define GLL16(g, l)                                                            \
    __builtin_amdgcn_global_load_lds(                                          \
        (const __attribute__((address_space(1))) void*)(g),                    \
        (__attribute__((address_space(3))) void*)(l), 16, 0, 0)

// ---- prep: fused  x->bf16 convert | bucket histogram | W1 pack | W2 pack ----
__global__ void prep_kernel(const float* __restrict__ x, unsigned short* __restrict__ x_bf,
                            const float* __restrict__ W1, unsigned short* __restrict__ Wp1,
                            const float* __restrict__ W2, unsigned short* __restrict__ Wp2,
                            const int* __restrict__ ni, const int* __restrict__ hi,
                            int* __restrict__ bcntN, int* __restrict__ bcntH) {
    const int blk = blockIdx.x;
    const int t = threadIdx.x;
    if (blk < CVT_BLK) {
        const long i = (long)blk * 256 + t;
        const float4 v = *(const float4*)(x + i * 4);
        ushort4 o;
        o.x = f2bf(v.x); o.y = f2bf(v.y); o.z = f2bf(v.z); o.w = f2bf(v.w);
        *(ushort4*)(x_bf + i * 4) = o;
    } else if (blk < CVT_BLK + BH_BLK) {
        __shared__ int lh[NBK], ln[NBK];
        for (int k = t; k < NBK; k += 256) { lh[k] = 0; ln[k] = 0; }
        __syncthreads();
        const int bb = blk - CVT_BLK;
        for (int i4 = bb * 256 + t; i4 < NNZ_ / 4; i4 += BH_BLK * 256) {
            const int4 nv = *(const int4*)(ni + i4 * 4);
            const int4 hv = *(const int4*)(hi + i4 * 4);
            atomicAdd(&ln[nv.x >> 7], 1); atomicAdd(&ln[nv.y >> 7], 1);
            atomicAdd(&ln[nv.z >> 7], 1); atomicAdd(&ln[nv.w >> 7], 1);
            atomicAdd(&lh[hv.x >> 7], 1); atomicAdd(&lh[hv.y >> 7], 1);
            atomicAdd(&lh[hv.z >> 7], 1); atomicAdd(&lh[hv.w >> 7], 1);
        }
        __syncthreads();
        for (int k = t; k < NBK; k += 256) {
            if (ln[k]) atomicAdd(&bcntN[k], ln[k]);
            if (lh[k]) atomicAdd(&bcntH[k], lh[k]);
        }
    } else if (blk < CVT_BLK + BH_BLK + PK1_BLK) {
        const int i = (blk - (CVT_BLK + BH_BLK)) * 256 + t;
        const int kt = i / (HID_CH * 32);
        const int r  = i % (HID_CH * 32);
        const int n  = r >> 5, kk = r & 31;
        Wp1[i] = f2bf(W1[(size_t)(kt * 32 + kk) * HID_CH + n]);
    } else {
        const int i = (blk - (CVT_BLK + BH_BLK + PK1_BLK)) * 256 + t;
        const int kt = i / (OUT_CH * 32);
        const int r  = i % (OUT_CH * 32);
        const int n  = r >> 5, kk = r & 31;
        Wp2[i] = f2bf(W2[(size_t)(kt * 32 + kk) * OUT_CH + n]);
    }
}

// ---- 391-entry exclusive scan; writes bucket starts + a mutable cursor copy ----
__global__ void scan391_kernel(const int* __restrict__ cA, int* __restrict__ offA,
                               int* __restrict__ curA,
                               const int* __restrict__ cB, int* __restrict__ offB,
                               int* __restrict__ curB) {
    const int* cnt = blockIdx.x ? cB : cA;
    int* off = blockIdx.x ? offB : offA;
    int* cur = blockIdx.x ? curB : curA;
    __shared__ int sbuf[512];
    const int t = threadIdx.x;      // 512 threads
    const int v = (t < NBK) ? cnt[t] : 0;
    sbuf[t] = v;
    __syncthreads();
    #pragma unroll
    for (int d = 1; d < 512; d <<= 1) {
        int u = (t >= d) ? sbuf[t - d] : 0;
        __syncthreads();
        sbuf[t] += u;
        __syncthreads();
    }
    if (t < NBK) { off[t] = sbuf[t] - v; cur[t] = sbuf[t] - v; }
    if (t == NBK - 1) off[NBK] = sbuf[t];
}

// ---- bin: scatter packed records into bucket slices (mutates bcur cursors) ----
__global__ void bin_kernel(const int* __restrict__ ni, const int* __restrict__ hi,
                           int* __restrict__ bcurN, int* __restrict__ bcurH,
                           unsigned* __restrict__ recN, unsigned* __restrict__ recH) {
    __shared__ int cH[NBK], cN[NBK], bH[NBK], bN[NBK];
    for (int t = threadIdx.x; t < NBK; t += blockDim.x) { cH[t] = 0; cN[t] = 0; }
    __syncthreads();
    const int gid = blockIdx.x * blockDim.x + threadIdx.x;
    const int i0 = gid * 4;
    int4 nv, hv;
    const bool act = (i0 < NNZ_);
    if (act) {
        nv = *(const int4*)(ni + i0);
        hv = *(const int4*)(hi + i0);
        atomicAdd(&cN[nv.x >> 7], 1); atomicAdd(&cN[nv.y >> 7], 1);
        atomicAdd(&cN[nv.z >> 7], 1); atomicAdd(&cN[nv.w >> 7], 1);
        atomicAdd(&cH[hv.x >> 7], 1); atomicAdd(&cH[hv.y >> 7], 1);
        atomicAdd(&cH[hv.z >> 7], 1); atomicAdd(&cH[hv.w >> 7], 1);
    }
    __syncthreads();
    for (int t = threadIdx.x; t < NBK; t += blockDim.x) {
        bH[t] = cH[t] ? atomicAdd(&bcurH[t], cH[t]) : 0;
        bN[t] = cN[t] ? atomicAdd(&bcurN[t], cN[t]) : 0;
    }
    __syncthreads();
    for (int t = threadIdx.x; t < NBK; t += blockDim.x) { cH[t] = bH[t]; cN[t] = bN[t]; }
    __syncthreads();
    if (act) {
        int nn[4] = {nv.x, nv.y, nv.z, nv.w};
        int hh[4] = {hv.x, hv.y, hv.z, hv.w};
        #pragma unroll
        for (int k = 0; k < 4; ++k) {
            int p = atomicAdd(&cH[hh[k] >> 7], 1);
            recH[p] = ((unsigned)(hh[k] & 127) << 16) | (unsigned)nn[k];
            p = atomicAdd(&cN[nn[k] >> 7], 1);
            recN[p] = ((unsigned)(nn[k] & 127) << 16) | (unsigned)hh[k];
        }
    }
}

// ---- buildcsr: per bucket — count, 128-prefix-scan, off+inv write, col fill ----
__global__ void buildcsr_kernel(const int* __restrict__ bstartH, const unsigned* __restrict__ recH,
                                int* __restrict__ offH, int* __restrict__ colH,
                                float* __restrict__ Binv,
                                const int* __restrict__ bstartN, const unsigned* __restrict__ recN,
                                int* __restrict__ offN, int* __restrict__ colN,
                                float* __restrict__ Dinv) {
    int b = blockIdx.x;
    const int* bstart; const unsigned* rec; int* off; int* col; float* inv;
    if (b < NBK) { bstart = bstartH; rec = recH; off = offH; col = colH; inv = Binv; }
    else { b -= NBK; bstart = bstartN; rec = recN; off = offN; col = colN; inv = Dinv; }
    const int s = bstart[b], e = bstart[b + 1];
    const int t = threadIdx.x;
    __shared__ int lc[128], ps[128], cur[128];
    if (t < 128) lc[t] = 0;
    __syncthreads();
    for (int i = s + t; i < e; i += 256) atomicAdd(&lc[rec[i] >> 16], 1);
    __syncthreads();
    if (t < 128) ps[t] = lc[t];
    __syncthreads();
    #pragma unroll
    for (int d = 1; d < 128; d <<= 1) {
        int v = (t >= d && t < 128) ? ps[t - d] : 0;
        __syncthreads();
        if (t < 128) ps[t] += v;
        __syncthreads();
    }
    if (t < 128) {
        const int excl = s + ps[t] - lc[t];
        cur[t] = excl;
        const int id = b * 128 + t;
        if (id < N_NODES) {
            off[id] = excl;
            inv[id] = lc[t] > 0 ? 1.f / (float)lc[t] : 0.f;
        }
    }
    if (b == NBK - 1 && t == 255) off[N_NODES] = bstart[NBK];
    __syncthreads();
    for (int i = s + t; i < e; i += 256) {
        const unsigned r = rec[i];
        const int p = atomicAdd(&cur[r >> 16], 1);
        col[p] = (int)(r & 0xFFFFu);
    }
}

// ---------------- MFMA bf16 GEMM: C[M,N] = A[M,K] @ W[K,N], bf16 output -----------
template <int BN>
__global__ void mfma_gemm_kernel(const unsigned short* __restrict__ A,
                                 const unsigned short* __restrict__ Wp,
                                 unsigned short* __restrict__ C, int M, int N, int K) {
    constexpr int NT = BN / 32;
    __shared__ unsigned short As[128 * 32];
    __shared__ unsigned short Bs[BN * 32];

    const int tid  = threadIdx.x;
    const int wave = tid >> 6;
    const int lane = tid & 63;
    const int wr = wave >> 1;
    const int wc = wave & 1;
    const int quad = lane >> 4;
    const int l15  = lane & 15;
    const int row0 = blockIdx.y * 128;
    const int col0 = blockIdx.x * BN;

    const size_t a_g0   = (size_t)(row0 + wave * 16 + (lane >> 2)) * K + (lane & 3) * 8;
    const int    a_l0   = (wave * 16 + (lane >> 2)) * 32 + (lane & 3) * 8;
    const size_t b_gbase = ((size_t)col0 + wave * 16 + (lane >> 2)) * 32 + (lane & 3) * 8;
    const int    b_l0   = (wave * 16 + (lane >> 2)) * 32 + (lane & 3) * 8;

    f32x4 acc[4][NT];
    #pragma unroll
    for (int mt = 0; mt < 4; ++mt)
        #pragma unroll
        for (int nt = 0; nt < NT; ++nt)
            acc[mt][nt] = (f32x4)0.f;

    const int KT = K / 32;
    for (int kt = 0; kt < KT; ++kt) {
        __syncthreads();
        GLL16(A + a_g0 + (size_t)kt * 32, As + a_l0);
        GLL16(A + a_g0 + (size_t)(kt * 32) + (size_t)64 * K, As + a_l0 + 64 * 32);
        const size_t bk = (size_t)kt * N * 32;
        GLL16(Wp + bk + b_gbase, Bs + b_l0);
        if (BN == 128)
            GLL16(Wp + bk + b_gbase + 64 * 32, Bs + b_l0 + 64 * 32);
        __syncthreads();

        bf16x8 af[4], bf[NT];
        #pragma unroll
        for (int mt = 0; mt < 4; ++mt)
            af[mt] = *(const bf16x8*)(As + (wr * 64 + mt * 16 + l15) * 32 + quad * 8);
        #pragma unroll
        for (int nt = 0; nt < NT; ++nt)
            bf[nt] = *(const bf16x8*)(Bs + (wc * (BN / 2) + nt * 16 + l15) * 32 + quad * 8);
        #pragma unroll
        for (int mt = 0; mt < 4; ++mt)
            #pragma unroll
            for (int nt = 0; nt < NT; ++nt)
                acc[mt][nt] = __builtin_amdgcn_mfma_f32_16x16x32_bf16(
                    af[mt], bf[nt], acc[mt][nt], 0, 0, 0);
    }

    #pragma unroll
    for (int mt = 0; mt < 4; ++mt) {
        const int gr0 = row0 + wr * 64 + mt * 16 + quad * 4;
        #pragma unroll
        for (int nt = 0; nt < NT; ++nt) {
            const int gc = col0 + wc * (BN / 2) + nt * 16 + l15;
            #pragma unroll
            for (int r = 0; r < 4; ++r) {
                int gr = gr0 + r;
                if (gr < M) C[(size_t)gr * N + gc] = f2bf(acc[mt][nt][r]);
            }
        }
    }
}

// ---------------- gather segment-sum, 256 channels, bf16, 4-deep unrolled ----------
template <bool EPI>
__global__ void gather256_kernel(const unsigned short* __restrict__ src,
                                 unsigned short* __restrict__ dst,
                                 const int* __restrict__ off, const int* __restrict__ col,
                                 const float* __restrict__ scale,
                                 const float* __restrict__ bias, int nrows) {
    int row = blockIdx.x * (blockDim.x >> 6) + (threadIdx.x >> 6);
    if (row >= nrows) return;
    int lane = threadIdx.x & 63;
    int s = off[row], e = off[row + 1];
    float ax = 0.f, ay = 0.f, az = 0.f, aw = 0.f;
    int j = s;
    for (; j + 3 < e; j += 4) {
        const ushort4 u0 = *(const ushort4*)(src + (size_t)col[j]     * HID_CH + (lane << 2));
        const ushort4 u1 = *(const ushort4*)(src + (size_t)col[j + 1] * HID_CH + (lane << 2));
        const ushort4 u2 = *(const ushort4*)(src + (size_t)col[j + 2] * HID_CH + (lane << 2));
        const ushort4 u3 = *(const ushort4*)(src + (size_t)col[j + 3] * HID_CH + (lane << 2));
        ax += (bf2f(u0.x) + bf2f(u1.x)) + (bf2f(u2.x) + bf2f(u3.x));
        ay += (bf2f(u0.y) + bf2f(u1.y)) + (bf2f(u2.y) + bf2f(u3.y));
        az += (bf2f(u0.z) + bf2f(u1.z)) + (bf2f(u2.z) + bf2f(u3.z));
        aw += (bf2f(u0.w) + bf2f(u1.w)) + (bf2f(u2.w) + bf2f(u3.w));
    }
    for (; j < e; ++j) {
        const ushort4 u = *(const ushort4*)(src + (size_t)col[j] * HID_CH + (lane << 2));
        ax += bf2f(u.x); ay += bf2f(u.y); az += bf2f(u.z); aw += bf2f(u.w);
    }
    float sc = scale[row];
    float rx = ax * sc, ry = ay * sc, rz = az * sc, rw = aw * sc;
    if (EPI) {
        const float4 b = *(const float4*)(bias + (lane << 2));
        rx = fmaxf(rx + b.x, 0.f); ry = fmaxf(ry + b.y, 0.f);
        rz = fmaxf(rz + b.z, 0.f); rw = fmaxf(rw + b.w, 0.f);
    }
    ushort4 o;
    o.x = f2bf(rx); o.y = f2bf(ry); o.z = f2bf(rz); o.w = f2bf(rw);
    *(ushort4*)(dst + (size_t)row * HID_CH + (lane << 2)) = o;
}

// ------- gather segment-sum, 64 ch: 4 edges/wave (16-lane groups, ushort4/lane) ----
// group g = lane>>4 strides the segment by 4; lane l = lane&15 holds channels 4l..4l+3.
// Cross-group reduce via shfl_xor(16,32); only group 0 stores.
template <bool LSM>
__global__ void gather64_kernel(const unsigned short* __restrict__ src, void* __restrict__ dstv,
                                const int* __restrict__ off, const int* __restrict__ col,
                                const float* __restrict__ scale,
                                const float* __restrict__ bias, int nrows) {
    int row = blockIdx.x * (blockDim.x >> 6) + (threadIdx.x >> 6);
    if (row >= nrows) return;
    const int lane = threadIdx.x & 63;
    const int g = lane >> 4;
    const int l = lane & 15;
    const int s = off[row], e = off[row + 1];
    float a0 = 0.f, a1 = 0.f, a2 = 0.f, a3 = 0.f;
    int j = s + g;
    for (; j + 4 < e; j += 8) {
        const ushort4 u0 = *(const ushort4*)(src + ((size_t)col[j]     << 6) + (l << 2));
        const ushort4 u1 = *(const ushort4*)(src + ((size_t)col[j + 4] << 6) + (l << 2));
        a0 += bf2f(u0.x) + bf2f(u1.x); a1 += bf2f(u0.y) + bf2f(u1.y);
        a2 += bf2f(u0.z) + bf2f(u1.z); a3 += bf2f(u0.w) + bf2f(u1.w);
    }
    if (j < e) {
        const ushort4 u = *(const ushort4*)(src + ((size_t)col[j] << 6) + (l << 2));
        a0 += bf2f(u.x); a1 += bf2f(u.y); a2 += bf2f(u.z); a3 += bf2f(u.w);
    }
    // reduce the 4 edge-groups
    a0 += __shfl_xor(a0, 16); a1 += __shfl_xor(a1, 16);
    a2 += __shfl_xor(a2, 16); a3 += __shfl_xor(a3, 16);
    a0 += __shfl_xor(a0, 32); a1 += __shfl_xor(a1, 32);
    a2 += __shfl_xor(a2, 32); a3 += __shfl_xor(a3, 32);
    const float sc = scale[row];
    float v0 = a0 * sc, v1 = a1 * sc, v2 = a2 * sc, v3 = a3 * sc;
    if (LSM) {
        const float4 b = *(const float4*)(bias + (l << 2));
        v0 += b.x; v1 += b.y; v2 += b.z; v3 += b.w;
        float m = fmaxf(fmaxf(v0, v1), fmaxf(v2, v3));
        #pragma unroll
        for (int o = 8; o >= 1; o >>= 1) m = fmaxf(m, __shfl_xor(m, o));
        float su = expf(v0 - m) + expf(v1 - m) + expf(v2 - m) + expf(v3 - m);
        #pragma unroll
        for (int o = 8; o >= 1; o >>= 1) su += __shfl_xor(su, o);
        const float lg = m + logf(su);
        if (g == 0) {
            float4 o4;
            o4.x = v0 - lg; o4.y = v1 - lg; o4.z = v2 - lg; o4.w = v3 - lg;
            *(float4*)((float*)dstv + (size_t)row * OUT_CH + (l << 2)) = o4;
        }
    } else if (g == 0) {
        ushort4 o4;
        o4.x = f2bf(v0); o4.y = f2bf(v1); o4.z = f2bf(v2); o4.w = f2bf(v3);
        *(ushort4*)((unsigned short*)dstv + (size_t)row * OUT_CH + (l << 2)) = o4;
    }
}

extern "C" void kernel_launch(void* const* d_in, const int* in_sizes, int n_in,
                              void* d_out, int out_size, void* d_ws, size_t ws_size,
                              hipStream_t stream) {
    const float* x  = (const float*)d_in[0];
    const int*   ei = (const int*)d_in[1];
    const float* W1 = (const float*)d_in[2];
    const float* b1 = (const float*)d_in[3];
    const float* W2 = (const float*)d_in[4];
    const float* b2 = (const float*)d_in[5];
    float* out = (float*)d_out;

    const int* node_idx  = ei;
    const int* hedge_idx = ei + NNZ_;

    const size_t RCAP = (size_t)M_PAD * IN_CH / 2;   // floats; 51.25 MB per region
    float* regionA = (float*)d_ws;
    float* regionB = regionA + RCAP;
    float* Dinv = regionB + RCAP;
    float* Binv = Dinv + N_NODES;
    int* offN = (int*)(Binv + N_HEDGES);             // N_NODES+1
    int* offH = offN + N_NODES + 1;                  // N_HEDGES+1
    int* colN = offH + N_HEDGES + 1;                 // NNZ
    int* colH = colN + NNZ_;                         // NNZ
    unsigned short* Wp1 = (unsigned short*)(colH + NNZ_);
    unsigned short* Wp2 = Wp1 + IN_CH * HID_CH;
    int* bcntH   = (int*)(Wp2 + HID_CH * OUT_CH);    // 400
    int* bcntN   = bcntH + 400;                      // 400
    int* bstartH = bcntN + 400;                      // 392 used
    int* bstartN = bstartH + 400;
    int* bcurH   = bstartN + 400;
    int* bcurN   = bcurH + 400;

    // transient CSR-build records alias regionA (dead until GEMM1 writes h1)
    unsigned* recH = (unsigned*)regionA;             // NNZ
    unsigned* recN = recH + NNZ_;                    // NNZ

    unsigned short* x_bf  = (unsigned short*)regionB;            // M_PAD x 512
    unsigned short* h1_bf = (unsigned short*)regionA;            // M_PAD x 256
    unsigned short* m1_bf = (unsigned short*)regionB;            // 50000 x 256 (x dead)
    unsigned short* h2_bf = (unsigned short*)regionA;            // M_PAD x 256 (h1 dead)
    unsigned short* g_bf  = (unsigned short*)regionB;            // 50000 x 64 (m1 dead)
    unsigned short* m2_bf = (unsigned short*)regionB + (size_t)M_PAD * OUT_CH; // 50000 x 64

    // ---- fused prep + CSR build ----
    hipMemsetAsync(bcntH, 0, 800 * sizeof(int), stream);
    prep_kernel<<<CVT_BLK + BH_BLK + PK1_BLK + PK2_BLK, 256, 0, stream>>>(
        x, x_bf, W1, Wp1, W2, Wp2, node_idx, hedge_idx, bcntN, bcntH);
    scan391_kernel<<<2, 512, 0, stream>>>(bcntH, bstartH, bcurH, bcntN, bstartN, bcurN);
    bin_kernel<<<200, 1024, 0, stream>>>(node_idx, hedge_idx, bcurN, bcurH, recN, recH);
    buildcsr_kernel<<<2 * NBK, 256, 0, stream>>>(bstartH, recH, offH, colH, Binv,
                                                 bstartN, recN, offN, colN, Dinv);

    // ---- layer 1: h1 = x @ W1 (MFMA bf16) ----
    mfma_gemm_kernel<128><<<dim3(HID_CH / 128, (N_NODES + 127) / 128), 256, 0, stream>>>(
        x_bf, Wp1, h1_bf, N_NODES, HID_CH, IN_CH);
    gather256_kernel<false><<<(N_HEDGES + 3) / 4, 256, 0, stream>>>(
        h1_bf, m1_bf, offH, colH, Binv, nullptr, N_HEDGES);
    gather256_kernel<true><<<(N_NODES + 3) / 4, 256, 0, stream>>>(
        m1_bf, h2_bf, offN, colN, Dinv, b1, N_NODES);

    // ---- layer 2: g = h2 @ W2 (MFMA bf16) ----
    mfma_gemm_kernel<64><<<dim3(OUT_CH / 64, (N_NODES + 127) / 128), 256, 0, stream>>>(
        h2_bf, Wp2, g_bf, N_NODES, OUT_CH, HID_CH);
    gather64_kernel<false><<<(N_HEDGES + 3) / 4, 256, 0, stream>>>(
        g_bf, m2_bf, offH, colH, Binv, nullptr, N_HEDGES);
    gather64_kernel<true><<<(N_NODES + 3) / 4, 256, 0, stream>>>(
        m2_bf, out, offN, colN, Dinv, b2, N_NODES);
}